// Round 14
// baseline (129.813 us; speedup 1.0000x reference)
//
#include <hip/hip_runtime.h>
#include <hip/hip_bf16.h>

#define G_ 8
#define GIN_ 256
#define GOUT_ 256
#define NROWS_ 8192
#define LDX_ 2048   // = G_*GIN_ = row stride of x and out

typedef __attribute__((ext_vector_type(4))) float f32x4;
typedef __attribute__((ext_vector_type(8))) short bf16x8;

// ---------------------------------------------------------------------------
// Prep: W [G][GIN=k 256][GOUT=col 256] f32 -> WtB fragment-tiled bf16:
//   granule(g, c, cb, c16, quad) = W[g][k = c*32+quad*8 .. +8][col = cb*16+c16]
//   element offset = g*65536 + (c*16+cb)*512 + c16*32 + quad*8
// A wave's B-frag load (16 cols x 4 quads x 16B) is ONE contiguous 1 KB.
// (unchanged — harness-verified)
// ---------------------------------------------------------------------------
__global__ __launch_bounds__(256) void wprep_kernel(const float* __restrict__ W,
                                                    __hip_bfloat16* __restrict__ Wt) {
    __shared__ float tile[64][65];   // +1 pad
    const int bid = blockIdx.x;
    const int g  = bid >> 4;
    const int kt = (bid >> 2) & 3;   // k-tile (64 wide)
    const int ct = bid & 3;          // col-tile (64 wide)
    const float* Wg = W + g * (GIN_ * GOUT_);
    __hip_bfloat16* Wo = Wt + (size_t)g * (GIN_ * GOUT_);
    const int lane_o = threadIdx.x & 63;   // col within tile
    const int sub    = threadIdx.x >> 6;   // 0..3
#pragma unroll
    for (int r = 0; r < 16; ++r) {
        int i = r * 4 + sub;               // k within tile
        tile[i][lane_o] = Wg[(kt * 64 + i) * GOUT_ + ct * 64 + lane_o];
    }
    __syncthreads();
    const int col = threadIdx.x & 63;
    const int kgb = threadIdx.x >> 6;      // 0..3
#pragma unroll
    for (int h = 0; h < 2; ++h) {
        const int kg    = kgb + h * 4;     // 0..7: granule-of-8k in 64-k tile
        const int kglob = kt * 64 + kg * 8;
        const int c     = kglob >> 5;      // k-chunk 0..7
        const int quad  = (kglob >> 3) & 3;
        const int colg  = ct * 64 + col;
        const int cb    = colg >> 4;
        const int c16   = colg & 15;
        union { __hip_bfloat16 hh[8]; bf16x8 v; } cv;
#pragma unroll
        for (int j = 0; j < 8; ++j)
            cv.hh[j] = __float2bfloat16(tile[kg * 8 + j][col]);
        *(bf16x8*)(Wo + (size_t)(c * 16 + cb) * 512 + c16 * 32 + quad * 8) = cv.v;
    }
}

__device__ __forceinline__ bf16x8 cvt8(const f32x4 a, const f32x4 b) {
    union { __hip_bfloat16 h[8]; bf16x8 v; } u;
    u.h[0] = __float2bfloat16(a.x); u.h[1] = __float2bfloat16(a.y);
    u.h[2] = __float2bfloat16(a.z); u.h[3] = __float2bfloat16(a.w);
    u.h[4] = __float2bfloat16(b.x); u.h[5] = __float2bfloat16(b.y);
    u.h[6] = __float2bfloat16(b.z); u.h[7] = __float2bfloat16(b.w);
    return u.v;
}

// ---------------------------------------------------------------------------
// Main fused kernel — BLOCK-CHURN DMA PIPELINE (R14).
//  R13 == R12 exactly (flat): in-flight read depth (64 vs 96 KB/CU) is
//  saturated. Remaining mechanism: grid 512 = EXACT 2-blocks/CU capacity ->
//  all blocks start at t=0, zero churn, machine-wide phase-locked pipeline
//  (global DMA burst, then global compute) -> ~50% memory duty cycle.
//  One variable vs R13: block granularity. 1024 blocks x 64 rows (4 half-
//  slabs, 4 buffers — each used ONCE per block, trivially race-free; same
//  depth-3 prologue = same 48 KB/block in flight; 64 KB LDS -> 2 resident
//  + 2 QUEUED per CU). Blocks now turn over twice: an incoming block's
//  pure-DMA prologue interleaves with its neighbor's compute phase.
//  Issue ledger (consts/B older than all DMA; SB pins DMA-before-stores):
//    B,bias | D0,D1,D2 | D3,s0 | s1 | s2 | s3
//  gates ensure D(h) landed: prologue GATE(4); then GATE(6),GATE(6),GATE(6).
//  Everything else == R13 (verified): DMA swizzle geometry, B-resident,
//  swapped-operand MFMA (transposed C), f32x4 cached stores.
// Grid: 8 g x 128 rowblocks(64 rows) = 1024 blocks; bid&7 = g (Wt L2-local).
// ---------------------------------------------------------------------------
__global__ __launch_bounds__(512, 4) void gkan_kernel(const float* __restrict__ x,
                                                      const __hip_bfloat16* __restrict__ Wt,
                                                      const float* __restrict__ bias,
                                                      const float* __restrict__ pc,
                                                      const float* __restrict__ qc,
                                                      float* __restrict__ out) {
    __shared__ __align__(16) float As[4][16 * 256];   // 4 x 16 KB half-slabs

    const int bid  = blockIdx.x;
    const int g    = bid & 7;
    const int row0 = (bid >> 3) * 64;

    const int t    = threadIdx.x;
    const int wave = t >> 6;             // 0..7 -> cols [wave*32, +32)
    const int lane = t & 63;
    const int lm   = lane & 15;
    const int q    = lane >> 4;

    const float* xbase = x + (size_t)row0 * LDX_ + g * GIN_;
    const int gsrc = (lane & ~7) | ((lane & 7) ^ wave);   // inverse swizzle @src

#define SB() __builtin_amdgcn_sched_barrier(0)
#define GATE(N) asm volatile("s_waitcnt vmcnt(" #N ")\n\ts_barrier" ::: "memory")

    // half-slab hs (16 rows) -> buffer hs: 2 global_load_lds per thread.
    // round r_: row = hs*16 + r_*8 + wave (row&7 == wave); lane l covers LDS
    // 16B-slot l; src granule = (l&~7)|((l&7)^wave).
#define DMA_HS(hs)                                                            \
    {                                                                         \
        _Pragma("unroll")                                                     \
        for (int r_ = 0; r_ < 2; ++r_) {                                      \
            const float* src_ = xbase                                         \
                + (size_t)((hs) * 16 + r_ * 8 + wave) * LDX_ + gsrc * 4;      \
            __builtin_amdgcn_global_load_lds(                                 \
                (const __attribute__((address_space(1))) void*)src_,          \
                (__attribute__((address_space(3))) void*)                     \
                    ((char*)As + (hs) * 16384 + r_ * 8192 + t * 16),          \
                16, 0, 0);                                                    \
        }                                                                     \
    }

    // compute half-slab hs (8 chunks x 2 MFMA, swapped operands -> transposed
    // C) + epilogue (2 f32x4 stores).
#define DO_HS(hs)                                                             \
    {                                                                         \
        f32x4 acc0 = {0.f, 0.f, 0.f, 0.f}, acc1 = {0.f, 0.f, 0.f, 0.f};       \
        const char* ab_ = (const char*)As + (hs) * 16384 + lm * 1024;         \
        _Pragma("unroll")                                                     \
        for (int c_ = 0; c_ < 8; ++c_) {                                      \
            const int gg0_ = c_ * 8 + ((q * 2)     ^ (lm & 7));               \
            const int gg1_ = c_ * 8 + ((q * 2 + 1) ^ (lm & 7));               \
            const f32x4 lo_ = *(const f32x4*)(ab_ + gg0_ * 16);               \
            const f32x4 hi_ = *(const f32x4*)(ab_ + gg1_ * 16);               \
            const bf16x8 af_ = cvt8(lo_, hi_);                                \
            acc0 = __builtin_amdgcn_mfma_f32_16x16x32_bf16(B0[c_], af_, acc0, 0, 0, 0); \
            acc1 = __builtin_amdgcn_mfma_f32_16x16x32_bf16(B1[c_], af_, acc1, 0, 0, 0); \
        }                                                                     \
        const int row_o_ = row0 + (hs) * 16 + lm;                             \
        _Pragma("unroll")                                                     \
        for (int nt_ = 0; nt_ < 2; ++nt_) {                                   \
            const f32x4 a_ = nt_ ? acc1 : acc0;                               \
            f32x4 o_;                                                         \
            _Pragma("unroll")                                                 \
            for (int r_ = 0; r_ < 4; ++r_) {                                  \
                const float y_   = a_[r_] + bb4[nt_][r_];                     \
                const float num_ = p0 + y_ * (p1 + y_ * (p2 + y_ * p3));      \
                const float den_ = 1.0f + fabsf(y_ * (q0 + y_ * (q1 + y_ * q2))); \
                o_[r_] = num_ * __builtin_amdgcn_rcpf(den_);                  \
            }                                                                 \
            *(f32x4*)(out + (size_t)row_o_ * LDX_ + col0[nt_]) = o_;          \
        }                                                                     \
    }

    // ---- consts + B-resident FIRST (older than all DMA: out of gate counts)
    const __hip_bfloat16* bp = Wt + (size_t)g * (GIN_ * GOUT_)
                                  + (wave * 2) * 512 + lm * 32 + q * 8;
    bf16x8 B0[8], B1[8];
#pragma unroll
    for (int c = 0; c < 8; ++c) {
        B0[c] = *(const bf16x8*)(bp + (size_t)c * (16 * 512));
        B1[c] = *(const bf16x8*)(bp + (size_t)c * (16 * 512) + 512);
    }
    f32x4 bb4[2];
    int col0[2];
#pragma unroll
    for (int nt = 0; nt < 2; ++nt) {
        col0[nt] = g * GOUT_ + wave * 32 + nt * 16 + q * 4;
        bb4[nt]  = *(const f32x4*)(bias + col0[nt]);
    }
    const float p0 = pc[g * 4 + 0], p1 = pc[g * 4 + 1];
    const float p2 = pc[g * 4 + 2], p3 = pc[g * 4 + 3];
    const float q0 = qc[g * 3 + 0], q1 = qc[g * 3 + 1], q2 = qc[g * 3 + 2];
    SB();

    // ---- prologue DMA: hs0,1,2 (depth 3) ----
    DMA_HS(0); DMA_HS(1); DMA_HS(2);
    SB();
    GATE(4);                       // D0 landed (younger: D1,D2 = 4)

    // ---- 4-stage pipeline, per-gate exact vmcnt ----
    DMA_HS(3); SB(); DO_HS(0); GATE(6);   // D1 landed (younger: D2,D3,s0 = 6)
    DO_HS(1); GATE(6);                    // D2 landed (younger: D3,s0,s1 = 6)
    DO_HS(2); GATE(6);                    // D3 landed (younger: s0,s1,s2 = 6)
    DO_HS(3);                             // stores drain at kernel end

#undef DMA_HS
#undef DO_HS
#undef GATE
#undef SB
}

extern "C" void kernel_launch(void* const* d_in, const int* in_sizes, int n_in,
                              void* d_out, int out_size, void* d_ws, size_t ws_size,
                              hipStream_t stream) {
    const float* x = (const float*)d_in[0];
    const float* W = (const float*)d_in[1];
    const float* b = (const float*)d_in[2];
    const float* p = (const float*)d_in[3];
    const float* q = (const float*)d_in[4];
    float* out = (float*)d_out;

    __hip_bfloat16* Wt = (__hip_bfloat16*)d_ws;   // 1 MiB fragment-tiled bf16 W

    wprep_kernel<<<128, 256, 0, stream>>>(W, Wt);
    gkan_kernel<<<1024, 512, 0, stream>>>(x, Wt, b, p, q, out);
}

// Round 15
// 126.372 us; speedup vs baseline: 1.0272x; 1.0272x over previous
//
#include <hip/hip_runtime.h>
#include <hip/hip_bf16.h>

#define G_ 8
#define GIN_ 256
#define GOUT_ 256
#define NROWS_ 8192
#define LDX_ 2048   // = G_*GIN_ = row stride of x and out

typedef __attribute__((ext_vector_type(4))) float f32x4;
typedef __attribute__((ext_vector_type(8))) short bf16x8;

// ---------------------------------------------------------------------------
// Prep: W [G][GIN=k 256][GOUT=col 256] f32 -> WtB fragment-tiled bf16:
//   granule(g, c, cb, c16, quad) = W[g][k = c*32+quad*8 .. +8][col = cb*16+c16]
//   element offset = g*65536 + (c*16+cb)*512 + c16*32 + quad*8
// A wave's B-frag load (16 cols x 4 quads x 16B) is ONE contiguous 1 KB.
// (unchanged — harness-verified)
// ---------------------------------------------------------------------------
__global__ __launch_bounds__(256) void wprep_kernel(const float* __restrict__ W,
                                                    __hip_bfloat16* __restrict__ Wt) {
    __shared__ float tile[64][65];   // +1 pad
    const int bid = blockIdx.x;
    const int g  = bid >> 4;
    const int kt = (bid >> 2) & 3;   // k-tile (64 wide)
    const int ct = bid & 3;          // col-tile (64 wide)
    const float* Wg = W + g * (GIN_ * GOUT_);
    __hip_bfloat16* Wo = Wt + (size_t)g * (GIN_ * GOUT_);
    const int lane_o = threadIdx.x & 63;   // col within tile
    const int sub    = threadIdx.x >> 6;   // 0..3
#pragma unroll
    for (int r = 0; r < 16; ++r) {
        int i = r * 4 + sub;               // k within tile
        tile[i][lane_o] = Wg[(kt * 64 + i) * GOUT_ + ct * 64 + lane_o];
    }
    __syncthreads();
    const int col = threadIdx.x & 63;
    const int kgb = threadIdx.x >> 6;      // 0..3
#pragma unroll
    for (int h = 0; h < 2; ++h) {
        const int kg    = kgb + h * 4;     // 0..7: granule-of-8k in 64-k tile
        const int kglob = kt * 64 + kg * 8;
        const int c     = kglob >> 5;      // k-chunk 0..7
        const int quad  = (kglob >> 3) & 3;
        const int colg  = ct * 64 + col;
        const int cb    = colg >> 4;
        const int c16   = colg & 15;
        union { __hip_bfloat16 hh[8]; bf16x8 v; } cv;
#pragma unroll
        for (int j = 0; j < 8; ++j)
            cv.hh[j] = __float2bfloat16(tile[kg * 8 + j][col]);
        *(bf16x8*)(Wo + (size_t)(c * 16 + cb) * 512 + c16 * 32 + quad * 8) = cv.v;
    }
}

__device__ __forceinline__ bf16x8 cvt8(const f32x4 a, const f32x4 b) {
    union { __hip_bfloat16 h[8]; bf16x8 v; } u;
    u.h[0] = __float2bfloat16(a.x); u.h[1] = __float2bfloat16(a.y);
    u.h[2] = __float2bfloat16(a.z); u.h[3] = __float2bfloat16(a.w);
    u.h[4] = __float2bfloat16(b.x); u.h[5] = __float2bfloat16(b.y);
    u.h[6] = __float2bfloat16(b.z); u.h[7] = __float2bfloat16(b.w);
    return u.v;
}

// ---------------------------------------------------------------------------
// Main fused kernel — DEPTH-3 HALF-SLAB DMA PIPELINE (R13 = best verified).
//  Final state after the R0-R14 search. The one mechanism that moved the
//  needle (R12: ~42 -> ~35 µs): COMPILER-PROOF issue placement via
//  global_load_lds (zero dest VGPRs) + counted-vmcnt gates, keeping the
//  HBM read stream continuously in flight across barriers. Reg-staged
//  prefetch could never do this (allocator collapsed it to 24-32 VGPRs,
//  observed 3x). Depth beyond 64 KB/CU: flat (R13==R12). Block churn:
//  negative (R14, +2.5 µs). Occupancy, B-residency, unroll depth, store
//  width/policy, stream topology, bank conflicts: all falsified R0-R11.
//  Structure: 4 x 16 KB half-slab buffers, hand-unrolled 8-stage pipeline,
//  prefetch depth 3 (48 KB/block x 2 blocks/CU in flight). vmcnt gates
//  compile-time exact; consts/B issued before all DMA (out of the counts);
//  sched_barrier(0) pins DMA-before-store issue order:
//   order: B,bias | D0,D1,D2 | D3,s0 | D4,s1 | D5,s2 | D6,s3 | D7,s4 |s5|s6|s7
//   gate ensures D(h+1) landed; N = #younger ops: pro:4,6,8,10,10,10,8,6.
//  Buffer reuse race-free: DMA(h+4) targets buf (h-1)&3, whose readers all
//  passed gate(h-1).
// Grid: 8 g x 64 rowblocks(128 rows) = 512 blocks; bid&7 = g (Wt L2-local).
// ---------------------------------------------------------------------------
__global__ __launch_bounds__(512, 4) void gkan_kernel(const float* __restrict__ x,
                                                      const __hip_bfloat16* __restrict__ Wt,
                                                      const float* __restrict__ bias,
                                                      const float* __restrict__ pc,
                                                      const float* __restrict__ qc,
                                                      float* __restrict__ out) {
    __shared__ __align__(16) float As[4][16 * 256];   // 4 x 16 KB half-slabs

    const int bid  = blockIdx.x;
    const int g    = bid & 7;
    const int row0 = (bid >> 3) * 128;

    const int t    = threadIdx.x;
    const int wave = t >> 6;             // 0..7 -> cols [wave*32, +32)
    const int lane = t & 63;
    const int lm   = lane & 15;
    const int q    = lane >> 4;

    const float* xbase = x + (size_t)row0 * LDX_ + g * GIN_;
    const int gsrc = (lane & ~7) | ((lane & 7) ^ wave);   // inverse swizzle @src

#define SB() __builtin_amdgcn_sched_barrier(0)
#define GATE(N) asm volatile("s_waitcnt vmcnt(" #N ")\n\ts_barrier" ::: "memory")

    // half-slab hs (16 rows) -> buffer buf: 2 global_load_lds per thread.
    // round r_: row = hs*16 + r_*8 + wave (row&7 == wave); lane l covers LDS
    // 16B-slot l; src granule = (l&~7)|((l&7)^wave).
#define DMA_HS(hs, buf)                                                       \
    {                                                                         \
        _Pragma("unroll")                                                     \
        for (int r_ = 0; r_ < 2; ++r_) {                                      \
            const float* src_ = xbase                                         \
                + (size_t)((hs) * 16 + r_ * 8 + wave) * LDX_ + gsrc * 4;      \
            __builtin_amdgcn_global_load_lds(                                 \
                (const __attribute__((address_space(1))) void*)src_,          \
                (__attribute__((address_space(3))) void*)                     \
                    ((char*)As + (buf) * 16384 + r_ * 8192 + t * 16),         \
                16, 0, 0);                                                    \
        }                                                                     \
    }

    // compute half-slab hs from buffer buf (8 chunks x 2 MFMA, swapped
    // operands -> transposed C) + epilogue (2 f32x4 stores).
#define DO_HS(hs, buf)                                                        \
    {                                                                         \
        f32x4 acc0 = {0.f, 0.f, 0.f, 0.f}, acc1 = {0.f, 0.f, 0.f, 0.f};       \
        const char* ab_ = (const char*)As + (buf) * 16384 + lm * 1024;        \
        _Pragma("unroll")                                                     \
        for (int c_ = 0; c_ < 8; ++c_) {                                      \
            const int gg0_ = c_ * 8 + ((q * 2)     ^ (lm & 7));               \
            const int gg1_ = c_ * 8 + ((q * 2 + 1) ^ (lm & 7));               \
            const f32x4 lo_ = *(const f32x4*)(ab_ + gg0_ * 16);               \
            const f32x4 hi_ = *(const f32x4*)(ab_ + gg1_ * 16);               \
            const bf16x8 af_ = cvt8(lo_, hi_);                                \
            acc0 = __builtin_amdgcn_mfma_f32_16x16x32_bf16(B0[c_], af_, acc0, 0, 0, 0); \
            acc1 = __builtin_amdgcn_mfma_f32_16x16x32_bf16(B1[c_], af_, acc1, 0, 0, 0); \
        }                                                                     \
        const int row_o_ = row0 + (hs) * 16 + lm;                             \
        _Pragma("unroll")                                                     \
        for (int nt_ = 0; nt_ < 2; ++nt_) {                                   \
            const f32x4 a_ = nt_ ? acc1 : acc0;                               \
            f32x4 o_;                                                         \
            _Pragma("unroll")                                                 \
            for (int r_ = 0; r_ < 4; ++r_) {                                  \
                const float y_   = a_[r_] + bb4[nt_][r_];                     \
                const float num_ = p0 + y_ * (p1 + y_ * (p2 + y_ * p3));      \
                const float den_ = 1.0f + fabsf(y_ * (q0 + y_ * (q1 + y_ * q2))); \
                o_[r_] = num_ * __builtin_amdgcn_rcpf(den_);                  \
            }                                                                 \
            *(f32x4*)(out + (size_t)row_o_ * LDX_ + col0[nt_]) = o_;          \
        }                                                                     \
    }

    // ---- consts + B-resident FIRST (older than all DMA: out of gate counts)
    const __hip_bfloat16* bp = Wt + (size_t)g * (GIN_ * GOUT_)
                                  + (wave * 2) * 512 + lm * 32 + q * 8;
    bf16x8 B0[8], B1[8];
#pragma unroll
    for (int c = 0; c < 8; ++c) {
        B0[c] = *(const bf16x8*)(bp + (size_t)c * (16 * 512));
        B1[c] = *(const bf16x8*)(bp + (size_t)c * (16 * 512) + 512);
    }
    f32x4 bb4[2];
    int col0[2];
#pragma unroll
    for (int nt = 0; nt < 2; ++nt) {
        col0[nt] = g * GOUT_ + wave * 32 + nt * 16 + q * 4;
        bb4[nt]  = *(const f32x4*)(bias + col0[nt]);
    }
    const float p0 = pc[g * 4 + 0], p1 = pc[g * 4 + 1];
    const float p2 = pc[g * 4 + 2], p3 = pc[g * 4 + 3];
    const float q0 = qc[g * 3 + 0], q1 = qc[g * 3 + 1], q2 = qc[g * 3 + 2];
    SB();

    // ---- prologue DMA: hs0,1,2 (depth 3) ----
    DMA_HS(0, 0); DMA_HS(1, 1); DMA_HS(2, 2);
    SB();
    GATE(4);                       // D0 landed (younger: D1,D2 = 4)

    // ---- 8-stage pipeline, per-gate exact vmcnt ----
    DMA_HS(3, 3); SB(); DO_HS(0, 0); GATE(6);    // D1 (younger: D2,D3,s0)
    DMA_HS(4, 0); SB(); DO_HS(1, 1); GATE(8);    // D2 (D3,s0,D4,s1)
    DMA_HS(5, 1); SB(); DO_HS(2, 2); GATE(10);   // D3 (s0,D4,s1,D5,s2)
    DMA_HS(6, 2); SB(); DO_HS(3, 3); GATE(10);   // D4 (s1,D5,s2,D6,s3)
    DMA_HS(7, 3); SB(); DO_HS(4, 0); GATE(10);   // D5 (s2,D6,s3,D7,s4)
    DO_HS(5, 1); GATE(8);                        // D6 (s3,D7,s4,s5)
    DO_HS(6, 2); GATE(6);                        // D7 (s4,s5,s6)
    DO_HS(7, 3);                                 // stores drain at kernel end

#undef DMA_HS
#undef DO_HS
#undef GATE
#undef SB
}

extern "C" void kernel_launch(void* const* d_in, const int* in_sizes, int n_in,
                              void* d_out, int out_size, void* d_ws, size_t ws_size,
                              hipStream_t stream) {
    const float* x = (const float*)d_in[0];
    const float* W = (const float*)d_in[1];
    const float* b = (const float*)d_in[2];
    const float* p = (const float*)d_in[3];
    const float* q = (const float*)d_in[4];
    float* out = (float*)d_out;

    __hip_bfloat16* Wt = (__hip_bfloat16*)d_ws;   // 1 MiB fragment-tiled bf16 W

    wprep_kernel<<<128, 256, 0, stream>>>(W, Wt);
    gkan_kernel<<<512, 512, 0, stream>>>(x, Wt, b, p, q, out);
}